// Round 5
// baseline (457.938 us; speedup 1.0000x reference)
//
#include <hip/hip_runtime.h>

#define SEQ   2048
#define BATCH 4
#define NH    16
#define DM    1024
#define MTOT  (BATCH*SEQ)   // 8192

typedef unsigned short u16;
typedef unsigned int   u32;
typedef __attribute__((ext_vector_type(8))) __bf16 bf16x8;
typedef __attribute__((ext_vector_type(4))) float  f32x4;
typedef __attribute__((address_space(1))) u32 as1_u32;
typedef __attribute__((address_space(3))) u32 as3_u32;

__device__ __forceinline__ u16 f2bf(float f) {
  union { float f; u32 u; } c; c.f = f;
  return (u16)((c.u + 0x7fffu + ((c.u >> 16) & 1u)) >> 16);
}

__global__ void cast_bf16_k(const float* __restrict__ in, u16* __restrict__ out, int n4) {
  int i = blockIdx.x * blockDim.x + threadIdx.x;
  if (i < n4) {
    float4 v = reinterpret_cast<const float4*>(in)[i];
    ushort4 o;
    o.x = f2bf(v.x); o.y = f2bf(v.y); o.z = f2bf(v.z); o.w = f2bf(v.w);
    reinterpret_cast<ushort4*>(out)[i] = o;
  }
}

__global__ void rope_tab_k(const int* __restrict__ pos, float2* __restrict__ tab) {
  int i = blockIdx.x * blockDim.x + threadIdx.x;  // s*32 + j
  if (i < SEQ * 32) {
    int s = i >> 5, j = i & 31;
    float p = (float)pos[s];
    float fr = powf(10000.f, -(float)j / 32.f);
    float a = p * fr;
    tab[i] = make_float2(cosf(a), sinf(a));
  }
}

// C = A @ Bt^T.  A: [M,1024] bf16 row-major. Bt: [1024,1024] bf16 row-major ([N][K]).
// EPI 0: fp32 store to outF. EPI 1: z=0/1 -> RoPE -> Qh/Kh [B,H,S,64]; z=2 -> Vt [B,H,64,S].
// Q additionally scaled by 0.125*log2(e) so attention can use exp2 with no extra mult.
template<int EPI>
__global__ __launch_bounds__(256)
void gemm_bt(const u16* __restrict__ A,
             const u16* __restrict__ B0, const u16* __restrict__ B1, const u16* __restrict__ B2,
             float* __restrict__ outF,
             u16* __restrict__ Qh, u16* __restrict__ Kh, u16* __restrict__ Vt,
             const float2* __restrict__ tab) {
  const int K = DM, N = DM;
  __shared__ u16 lsA[128 * 32];
  __shared__ u16 lsB[128 * 32];
  const int t = threadIdx.x;
  const int lane = t & 63;
  const int wid = t >> 6;
  const int wr = wid >> 1, wc = wid & 1;
  const int m0 = blockIdx.y * 128, n0 = blockIdx.x * 128;
  const int z = blockIdx.z;
  const u16* Bt = (z == 0) ? B0 : (z == 1 ? B1 : B2);

  f32x4 acc[4][4] = {};

  const int srow = t >> 2;
  const int scol = (t & 3) * 8;
  const u16* gA = A + (size_t)(m0 + srow) * K + scol;
  const u16* gB = Bt + (size_t)(n0 + srow) * K + scol;
  const u32 lo = (u32)t * 16u;

  for (int kt = 0; kt < K; kt += 32) {
    __builtin_amdgcn_global_load_lds((const as1_u32*)(gA + kt),
                                     (as3_u32*)((char*)lsA + lo), 16, 0, 0);
    __builtin_amdgcn_global_load_lds((const as1_u32*)(gA + (size_t)64 * K + kt),
                                     (as3_u32*)((char*)lsA + 4096 + lo), 16, 0, 0);
    __builtin_amdgcn_global_load_lds((const as1_u32*)(gB + kt),
                                     (as3_u32*)((char*)lsB + lo), 16, 0, 0);
    __builtin_amdgcn_global_load_lds((const as1_u32*)(gB + (size_t)64 * K + kt),
                                     (as3_u32*)((char*)lsB + 4096 + lo), 16, 0, 0);
    __syncthreads();
    bf16x8 af[4], bfr[4];
#pragma unroll
    for (int mt = 0; mt < 4; ++mt)
      af[mt] = *(const bf16x8*)&lsA[(wr * 64 + mt * 16 + (lane & 15)) * 32 + (lane >> 4) * 8];
#pragma unroll
    for (int nt = 0; nt < 4; ++nt)
      bfr[nt] = *(const bf16x8*)&lsB[(wc * 64 + nt * 16 + (lane & 15)) * 32 + (lane >> 4) * 8];
#pragma unroll
    for (int mt = 0; mt < 4; ++mt)
#pragma unroll
      for (int nt = 0; nt < 4; ++nt)
        acc[mt][nt] = __builtin_amdgcn_mfma_f32_16x16x32_bf16(af[mt], bfr[nt], acc[mt][nt], 0, 0, 0);
    __syncthreads();
  }

#pragma unroll
  for (int mt = 0; mt < 4; ++mt) {
    const int gmb = m0 + wr * 64 + mt * 16 + (lane >> 4) * 4;
#pragma unroll
    for (int nt = 0; nt < 4; ++nt) {
      const int gn = n0 + wc * 64 + nt * 16 + (lane & 15);
#pragma unroll
      for (int r = 0; r < 4; ++r) {
        float v = acc[mt][nt][r];
        if (EPI == 0) {
          outF[(size_t)(gmb + r) * N + gn] = v;
        } else {
          const int row = gmb + r;
          const int b = row >> 11, s = row & (SEQ - 1);
          const int h = gn >> 6, dd = gn & 63;
          if (z < 2) {
            float p = __shfl_xor(v, 1);
            const float2 cs = tab[(s << 5) + (dd >> 1)];
            float o = ((lane & 1) == 0) ? (v * cs.x - p * cs.y) : (p * cs.y + v * cs.x);
            if (z == 0) o *= 0.18033688011112042f;  // 0.125 * log2(e)
            u16* dst = z ? Kh : Qh;
            dst[((size_t)((b * NH + h) * SEQ + s) << 6) + dd] = f2bf(o);
          } else {
            Vt[((size_t)((b * NH + h) << 6) + dd) * SEQ + s] = f2bf(v);
          }
        }
      }
    }
  }
}

// Flash attention, causal, log2-domain softmax, SPLIT-K across the block's 4 waves.
// Grid: 4096 blocks = (bh 64) x (chunk-rank 64), heavy chunks first.
// Block handles one 32-row q-chunk; wave w processes K-tiles kt = w, w+4, ...
// then partials (m,l,O) are combined through LDS. Longest serial chain: 8 tiles.
// NOTE: no min-waves launch_bounds -- forcing 4/EU spilled ~1GB to scratch (R3).
#define OST 68   // f32 stride of a partial-O row (64 + 4: 16B-aligned, bank-shifted)
__global__ __launch_bounds__(256)
void attn_k(const u16* __restrict__ Qh, const u16* __restrict__ Kh,
            const u16* __restrict__ Vt, u16* __restrict__ AO) {
  __shared__ float smem[4 * 32 * OST + 4 * 32 * 2];  // partial O [4][32][OST] + (m,l) [4][32][2]
  const int t = threadIdx.x, lane = t & 63, w = t >> 6;
  const int bid = blockIdx.x;
  const int bh = bid & 63, b = bh >> 4, h = bh & 15;
  const int chunk = 63 - (bid >> 6);          // heavy-first
  const int qbase = chunk * 32;
  const int tend = (qbase + 31) >> 6;         // last K-tile index (diagonal tile)
  const u16* Qp = Qh + (size_t)bh * SEQ * 64;
  const u16* Kp = Kh + (size_t)bh * SEQ * 64;
  const u16* Vp = Vt + (size_t)bh * 64 * SEQ;
  u16* Pw = (u16*)smem + w * 2304;            // per-wave 32x72 P buffer (aliases O region)
  float* Om = smem;                           // [4][32][OST]
  float* Ml = smem + 4 * 32 * OST;            // [4][32][2]

  bf16x8 qa[2][2];
#pragma unroll
  for (int mt = 0; mt < 2; ++mt)
#pragma unroll
    for (int kk = 0; kk < 2; ++kk)
      qa[mt][kk] = *(const bf16x8*)(Qp + (size_t)(qbase + mt * 16 + (lane & 15)) * 64 + kk * 32 + (lane >> 4) * 8);

  f32x4 oacc[2][4] = {};
  float mrun[2][4], lrun[2][4];
#pragma unroll
  for (int mt = 0; mt < 2; ++mt)
#pragma unroll
    for (int r = 0; r < 4; ++r) { mrun[mt][r] = -1e30f; lrun[mt][r] = 0.f; }

  // prefetch this wave's first K tile (kt = w; rows w*64 < SEQ always in-bounds)
  bf16x8 kb[4][2];
#pragma unroll
  for (int nt = 0; nt < 4; ++nt)
#pragma unroll
    for (int kk = 0; kk < 2; ++kk)
      kb[nt][kk] = *(const bf16x8*)(Kp + (size_t)(w * 64 + nt * 16 + (lane & 15)) * 64 + kk * 32 + (lane >> 4) * 8);

  for (int kt = w; kt <= tend; kt += 4) {
    const int k0 = kt * 64;

    // issue V loads early -- they fly during QK + softmax
    bf16x8 vb[4][2];
#pragma unroll
    for (int nt = 0; nt < 4; ++nt) {
      const size_t vrow = (size_t)(nt * 16 + (lane & 15)) * SEQ + k0 + (lane >> 4) * 8;
      vb[nt][0] = *(const bf16x8*)(Vp + vrow);
      vb[nt][1] = *(const bf16x8*)(Vp + vrow + 32);
    }

    f32x4 sc[2][4];
#pragma unroll
    for (int mt = 0; mt < 2; ++mt)
#pragma unroll
      for (int nt = 0; nt < 4; ++nt) {
        f32x4 a = {0.f, 0.f, 0.f, 0.f};
        a = __builtin_amdgcn_mfma_f32_16x16x32_bf16(qa[mt][0], kb[nt][0], a, 0, 0, 0);
        a = __builtin_amdgcn_mfma_f32_16x16x32_bf16(qa[mt][1], kb[nt][1], a, 0, 0, 0);
        sc[mt][nt] = a;
      }

    // prefetch this wave's next K tile while softmax runs
    if (kt + 4 <= tend) {
      const int kn = k0 + 256;
#pragma unroll
      for (int nt = 0; nt < 4; ++nt)
#pragma unroll
        for (int kk = 0; kk < 2; ++kk)
          kb[nt][kk] = *(const bf16x8*)(Kp + (size_t)(kn + nt * 16 + (lane & 15)) * 64 + kk * 32 + (lane >> 4) * 8);
    }

    const bool diag = (kt == tend);
#pragma unroll
    for (int mt = 0; mt < 2; ++mt) {
#pragma unroll
      for (int r = 0; r < 4; ++r) {
        const int qr = qbase + mt * 16 + (lane >> 4) * 4 + r;
        float vmax = -1e30f;
        if (diag) {
#pragma unroll
          for (int nt = 0; nt < 4; ++nt) {
            const int col = k0 + nt * 16 + (lane & 15);
            float sv = (col > qr) ? -1e30f : sc[mt][nt][r];
            sc[mt][nt][r] = sv;
            vmax = fmaxf(vmax, sv);
          }
        } else {
#pragma unroll
          for (int nt = 0; nt < 4; ++nt) vmax = fmaxf(vmax, sc[mt][nt][r]);
        }
#pragma unroll
        for (int off = 1; off < 16; off <<= 1) vmax = fmaxf(vmax, __shfl_xor(vmax, off));
        // defer-max (T13): rescale only when tile max exceeds running max by >7 (log2 domain)
        float m = mrun[mt][r];
        if (vmax > m + 7.f) {
          const float al = exp2f(m - vmax);
          mrun[mt][r] = vmax; m = vmax;
          lrun[mt][r] *= al;
#pragma unroll
          for (int nt = 0; nt < 4; ++nt) oacc[mt][nt][r] *= al;
        }
        float rs = 0.f;
#pragma unroll
        for (int nt = 0; nt < 4; ++nt) {
          float p = exp2f(sc[mt][nt][r] - m);
          sc[mt][nt][r] = p;
          rs += p;
        }
#pragma unroll
        for (int off = 1; off < 16; off <<= 1) rs += __shfl_xor(rs, off);
        lrun[mt][r] += rs;
      }
    }

    // P (D-frag layout) -> LDS -> A-frag layout (per-wave private buffer)
#pragma unroll
    for (int mt = 0; mt < 2; ++mt)
#pragma unroll
      for (int nt = 0; nt < 4; ++nt)
#pragma unroll
        for (int r = 0; r < 4; ++r)
          Pw[(mt * 16 + (lane >> 4) * 4 + r) * 72 + nt * 16 + (lane & 15)] = f2bf(sc[mt][nt][r]);
    asm volatile("s_waitcnt lgkmcnt(0)" ::: "memory");
    __builtin_amdgcn_sched_barrier(0);

    bf16x8 pa[2][2];
#pragma unroll
    for (int mt = 0; mt < 2; ++mt)
#pragma unroll
      for (int kk = 0; kk < 2; ++kk)
        pa[mt][kk] = *(const bf16x8*)&Pw[(mt * 16 + (lane & 15)) * 72 + kk * 32 + (lane >> 4) * 8];
    __builtin_amdgcn_sched_barrier(0);

#pragma unroll
    for (int nt = 0; nt < 4; ++nt)
#pragma unroll
      for (int mt = 0; mt < 2; ++mt) {
        oacc[mt][nt] = __builtin_amdgcn_mfma_f32_16x16x32_bf16(pa[mt][0], vb[nt][0], oacc[mt][nt], 0, 0, 0);
        oacc[mt][nt] = __builtin_amdgcn_mfma_f32_16x16x32_bf16(pa[mt][1], vb[nt][1], oacc[mt][nt], 0, 0, 0);
      }
  }

  // ---- combine the 4 waves' partials ----
  __syncthreads();  // everyone done with P buffers
#pragma unroll
  for (int mt = 0; mt < 2; ++mt)
#pragma unroll
    for (int r = 0; r < 4; ++r) {
      const int row = mt * 16 + (lane >> 4) * 4 + r;
#pragma unroll
      for (int nt = 0; nt < 4; ++nt)
        Om[(w * 32 + row) * OST + nt * 16 + (lane & 15)] = oacc[mt][nt][r];
      if ((lane & 15) == 0) {
        Ml[(w * 32 + row) * 2 + 0] = mrun[mt][r];
        Ml[(w * 32 + row) * 2 + 1] = lrun[mt][r];
      }
    }
  __syncthreads();

  // wave w merges rows w*8 .. w*8+7; lane handles row w*8+(lane>>3), cols (lane&7)*8..+7
  {
    const int row = w * 8 + (lane >> 3);
    const int c0 = (lane & 7) * 8;
    float mstar = -1e30f;
    float mp[4];
#pragma unroll
    for (int p = 0; p < 4; ++p) {
      mp[p] = Ml[(p * 32 + row) * 2 + 0];
      mstar = fmaxf(mstar, mp[p]);
    }
    float lstar = 0.f;
    float o[8] = {0.f, 0.f, 0.f, 0.f, 0.f, 0.f, 0.f, 0.f};
#pragma unroll
    for (int p = 0; p < 4; ++p) {
      const float sc = exp2f(mp[p] - mstar);
      lstar += Ml[(p * 32 + row) * 2 + 1] * sc;
      const float* Orow = &Om[(p * 32 + row) * OST + c0];
      f32x4 a = *(const f32x4*)Orow;
      f32x4 bq = *(const f32x4*)(Orow + 4);
#pragma unroll
      for (int j = 0; j < 4; ++j) { o[j] += a[j] * sc; o[4 + j] += bq[j] * sc; }
    }
    const float inv = 1.f / lstar;
    const int s = qbase + row;
    ushort4 pk0, pk1;
    pk0.x = f2bf(o[0] * inv); pk0.y = f2bf(o[1] * inv);
    pk0.z = f2bf(o[2] * inv); pk0.w = f2bf(o[3] * inv);
    pk1.x = f2bf(o[4] * inv); pk1.y = f2bf(o[5] * inv);
    pk1.z = f2bf(o[6] * inv); pk1.w = f2bf(o[7] * inv);
    u16* dst = AO + ((size_t)(b * SEQ + s) * NH + h) * 64 + c0;
    *reinterpret_cast<ushort4*>(dst) = pk0;
    *reinterpret_cast<ushort4*>(dst + 4) = pk1;
  }
}

extern "C" void kernel_launch(void* const* d_in, const int* in_sizes, int n_in,
                              void* d_out, int out_size, void* d_ws, size_t ws_size,
                              hipStream_t stream) {
  const float* x  = (const float*)d_in[0];
  const int*   pos = (const int*)d_in[1];
  const float* Wq = (const float*)d_in[2];
  const float* Wk = (const float*)d_in[3];
  const float* Wv = (const float*)d_in[4];
  const float* Wo = (const float*)d_in[5];
  float* out = (float*)d_out;
  char* ws = (char*)d_ws;
  const size_t MB = 1024 * 1024;
  if (ws_size < 73 * MB) return;  // refuse to scribble OOB

  u16* xb  = (u16*)(ws);             // 16MB; re-used as AO after QKV proj
  u16* wqb = (u16*)(ws + 16 * MB);
  u16* wkb = (u16*)(ws + 18 * MB);
  u16* wvb = (u16*)(ws + 20 * MB);
  u16* wob = (u16*)(ws + 22 * MB);
  u16* Qh  = (u16*)(ws + 24 * MB);
  u16* Kh  = (u16*)(ws + 40 * MB);
  u16* Vt  = (u16*)(ws + 56 * MB);
  float2* tab = (float2*)(ws + 72 * MB);
  u16* AO = xb;

  cast_bf16_k<<<(MTOT * DM / 4) / 256, 256, 0, stream>>>(x, xb, MTOT * DM / 4);
  cast_bf16_k<<<(DM * DM / 4) / 256, 256, 0, stream>>>(Wq, wqb, DM * DM / 4);
  cast_bf16_k<<<(DM * DM / 4) / 256, 256, 0, stream>>>(Wk, wkb, DM * DM / 4);
  cast_bf16_k<<<(DM * DM / 4) / 256, 256, 0, stream>>>(Wv, wvb, DM * DM / 4);
  cast_bf16_k<<<(DM * DM / 4) / 256, 256, 0, stream>>>(Wo, wob, DM * DM / 4);
  rope_tab_k<<<(SEQ * 32) / 256, 256, 0, stream>>>(pos, tab);

  gemm_bt<1><<<dim3(8, 64, 3), 256, 0, stream>>>(xb, wqb, wkb, wvb, nullptr, Qh, Kh, Vt, tab);
  attn_k<<<dim3(4096), 256, 0, stream>>>(Qh, Kh, Vt, AO);
  gemm_bt<0><<<dim3(8, 64, 1), 256, 0, stream>>>(AO, wob, wob, wob, out, nullptr, nullptr, nullptr, nullptr);
}

// Round 6
// 301.573 us; speedup vs baseline: 1.5185x; 1.5185x over previous
//
#include <hip/hip_runtime.h>

#define SEQ   2048
#define BATCH 4
#define NH    16
#define DM    1024
#define MTOT  (BATCH*SEQ)   // 8192

typedef unsigned short u16;
typedef unsigned int   u32;
typedef __attribute__((ext_vector_type(8))) __bf16 bf16x8;
typedef __attribute__((ext_vector_type(4))) float  f32x4;
typedef __attribute__((address_space(1))) u32 as1_u32;
typedef __attribute__((address_space(3))) u32 as3_u32;

__device__ __forceinline__ u16 f2bf(float f) {
  union { float f; u32 u; } c; c.f = f;
  return (u16)((c.u + 0x7fffu + ((c.u >> 16) & 1u)) >> 16);
}

__global__ void cast_bf16_k(const float* __restrict__ in, u16* __restrict__ out, int n4) {
  int i = blockIdx.x * blockDim.x + threadIdx.x;
  if (i < n4) {
    float4 v = reinterpret_cast<const float4*>(in)[i];
    ushort4 o;
    o.x = f2bf(v.x); o.y = f2bf(v.y); o.z = f2bf(v.z); o.w = f2bf(v.w);
    reinterpret_cast<ushort4*>(out)[i] = o;
  }
}

__global__ void rope_tab_k(const int* __restrict__ pos, float2* __restrict__ tab) {
  int i = blockIdx.x * blockDim.x + threadIdx.x;  // s*32 + j
  if (i < SEQ * 32) {
    int s = i >> 5, j = i & 31;
    float p = (float)pos[s];
    float fr = powf(10000.f, -(float)j / 32.f);
    float a = p * fr;
    tab[i] = make_float2(cosf(a), sinf(a));
  }
}

// C = A @ Bt^T.  A: [M,1024] bf16 row-major. Bt: [1024,1024] bf16 row-major ([N][K]).
// EPI 0: fp32 store to outF. EPI 1: z=0/1 -> RoPE -> Qh/Kh [B,H,S,64]; z=2 -> Vt [B,H,64,S].
// Q additionally scaled by 0.125*log2(e) so attention can use exp2 with no extra mult.
template<int EPI>
__global__ __launch_bounds__(256)
void gemm_bt(const u16* __restrict__ A,
             const u16* __restrict__ B0, const u16* __restrict__ B1, const u16* __restrict__ B2,
             float* __restrict__ outF,
             u16* __restrict__ Qh, u16* __restrict__ Kh, u16* __restrict__ Vt,
             const float2* __restrict__ tab) {
  const int K = DM, N = DM;
  __shared__ u16 lsA[128 * 32];
  __shared__ u16 lsB[128 * 32];
  const int t = threadIdx.x;
  const int lane = t & 63;
  const int wid = t >> 6;
  const int wr = wid >> 1, wc = wid & 1;
  const int m0 = blockIdx.y * 128, n0 = blockIdx.x * 128;
  const int z = blockIdx.z;
  const u16* Bt = (z == 0) ? B0 : (z == 1 ? B1 : B2);

  f32x4 acc[4][4] = {};

  const int srow = t >> 2;
  const int scol = (t & 3) * 8;
  const u16* gA = A + (size_t)(m0 + srow) * K + scol;
  const u16* gB = Bt + (size_t)(n0 + srow) * K + scol;
  const u32 lo = (u32)t * 16u;

  for (int kt = 0; kt < K; kt += 32) {
    __builtin_amdgcn_global_load_lds((const as1_u32*)(gA + kt),
                                     (as3_u32*)((char*)lsA + lo), 16, 0, 0);
    __builtin_amdgcn_global_load_lds((const as1_u32*)(gA + (size_t)64 * K + kt),
                                     (as3_u32*)((char*)lsA + 4096 + lo), 16, 0, 0);
    __builtin_amdgcn_global_load_lds((const as1_u32*)(gB + kt),
                                     (as3_u32*)((char*)lsB + lo), 16, 0, 0);
    __builtin_amdgcn_global_load_lds((const as1_u32*)(gB + (size_t)64 * K + kt),
                                     (as3_u32*)((char*)lsB + 4096 + lo), 16, 0, 0);
    __syncthreads();
    bf16x8 af[4], bfr[4];
#pragma unroll
    for (int mt = 0; mt < 4; ++mt)
      af[mt] = *(const bf16x8*)&lsA[(wr * 64 + mt * 16 + (lane & 15)) * 32 + (lane >> 4) * 8];
#pragma unroll
    for (int nt = 0; nt < 4; ++nt)
      bfr[nt] = *(const bf16x8*)&lsB[(wc * 64 + nt * 16 + (lane & 15)) * 32 + (lane >> 4) * 8];
#pragma unroll
    for (int mt = 0; mt < 4; ++mt)
#pragma unroll
      for (int nt = 0; nt < 4; ++nt)
        acc[mt][nt] = __builtin_amdgcn_mfma_f32_16x16x32_bf16(af[mt], bfr[nt], acc[mt][nt], 0, 0, 0);
    __syncthreads();
  }

#pragma unroll
  for (int mt = 0; mt < 4; ++mt) {
    const int gmb = m0 + wr * 64 + mt * 16 + (lane >> 4) * 4;
#pragma unroll
    for (int nt = 0; nt < 4; ++nt) {
      const int gn = n0 + wc * 64 + nt * 16 + (lane & 15);
#pragma unroll
      for (int r = 0; r < 4; ++r) {
        float v = acc[mt][nt][r];
        if (EPI == 0) {
          outF[(size_t)(gmb + r) * N + gn] = v;
        } else {
          const int row = gmb + r;
          const int b = row >> 11, s = row & (SEQ - 1);
          const int h = gn >> 6, dd = gn & 63;
          if (z < 2) {
            float p = __shfl_xor(v, 1);
            const float2 cs = tab[(s << 5) + (dd >> 1)];
            float o = ((lane & 1) == 0) ? (v * cs.x - p * cs.y) : (p * cs.y + v * cs.x);
            if (z == 0) o *= 0.18033688011112042f;  // 0.125 * log2(e)
            u16* dst = z ? Kh : Qh;
            dst[((size_t)((b * NH + h) * SEQ + s) << 6) + dd] = f2bf(o);
          } else {
            Vt[((size_t)((b * NH + h) << 6) + dd) * SEQ + s] = f2bf(v);
          }
        }
      }
    }
  }
}

// Flash attention, causal, log2-domain softmax.
// Grid: 1024 blocks = (bh 64) x (chunk-rank 16), heavy chunks first (bid%8 = bh%8,
// XCD-uniform). Block owns 128 q-rows (4 waves x 32). K/V tiles (64x64 bf16 each)
// are staged block-shared in LDS via global_load_lds, double-buffered, one barrier
// per tile; LDS rows XOR-swizzled (byte ^= (row&7)<<4) via pre-swizzled global
// source addresses (write-side) + swizzled ds_read offsets (read-side).
// NOTE: no min-waves launch_bounds -- forcing 4/EU spilled ~1GB to scratch (R3).
__global__ __launch_bounds__(256)
void attn_k(const u16* __restrict__ Qh, const u16* __restrict__ Kh,
            const u16* __restrict__ Vt, u16* __restrict__ AO) {
  __shared__ u16 lsK[2][64 * 64];
  __shared__ u16 lsV[2][64 * 64];
  __shared__ u16 lsP[4][32 * 72];
  const int t = threadIdx.x, lane = t & 63, w = t >> 6;
  const int bid = blockIdx.x;
  const int bh = bid & 63, b = bh >> 4, h = bh & 15;
  const int chunk = 15 - (bid >> 6);          // heavy-first
  const int qb_blk = chunk * 128;
  const int tendB = (qb_blk + 127) >> 6;      // block's last K-tile
  const int qbase = qb_blk + w * 32;          // this wave's rows
  const int tendW = (qbase + 31) >> 6;        // this wave's last K-tile
  const u16* Qp = Qh + (size_t)bh * SEQ * 64;
  const u16* Kp = Kh + (size_t)bh * SEQ * 64;
  const u16* Vp = Vt + (size_t)bh * 64 * SEQ;
  u16* Pw = &lsP[w][0];

  bf16x8 qa[2][2];
#pragma unroll
  for (int mt = 0; mt < 2; ++mt)
#pragma unroll
    for (int kk = 0; kk < 2; ++kk)
      qa[mt][kk] = *(const bf16x8*)(Qp + (size_t)(qbase + mt * 16 + (lane & 15)) * 64 + kk * 32 + (lane >> 4) * 8);

  f32x4 oacc[2][4] = {};
  float mrun[2][4], lrun[2][4];
#pragma unroll
  for (int mt = 0; mt < 2; ++mt)
#pragma unroll
    for (int r = 0; r < 4; ++r) { mrun[mt][r] = -1e30f; lrun[mt][r] = 0.f; }

  // ---- stage tile kt into buffer bf (all 256 threads cooperate) ----
  // LDS layout: linear dest; logical col-byte c stored at inrow position
  // c ^ ((row&7)<<4). Writer fetches global col (pos ^ ((row&7)<<4)).
#define STAGE(bf, kt_)                                                                  \
  {                                                                                     \
    const int k0s = (kt_) * 64;                                                         \
    _Pragma("unroll")                                                                   \
    for (int hh = 0; hh < 2; ++hh) {                                                    \
      const int idx = hh * 256 + t;                                                     \
      const int row = idx >> 3;                                                         \
      const int cb = ((idx & 7) << 4) ^ ((row & 7) << 4);                               \
      __builtin_amdgcn_global_load_lds((const as1_u32*)(Kp + (size_t)(k0s + row) * 64 + (cb >> 1)), \
                                       (as3_u32*)((char*)&lsK[bf][0] + idx * 16), 16, 0, 0); \
      __builtin_amdgcn_global_load_lds((const as1_u32*)(Vp + (size_t)row * SEQ + k0s + (cb >> 1)), \
                                       (as3_u32*)((char*)&lsV[bf][0] + idx * 16), 16, 0, 0); \
    }                                                                                   \
  }

  STAGE(0, 0);
  __syncthreads();  // drains vmcnt -> tile 0 resident
  int cur = 0;

  for (int kt = 0; kt <= tendB; ++kt) {
    if (kt < tendB) STAGE(cur ^ 1, kt + 1);  // next tile DMAs during compute

    if (kt <= tendW) {
      const int k0 = kt * 64;
      // K frags from LDS (swizzled read offsets)
      bf16x8 kb[4][2];
#pragma unroll
      for (int nt = 0; nt < 4; ++nt)
#pragma unroll
        for (int kk = 0; kk < 2; ++kk) {
          const int row = nt * 16 + (lane & 15);
          const int cb = (kk * 64 + ((lane >> 4) << 4)) ^ ((row & 7) << 4);
          kb[nt][kk] = *(const bf16x8*)&lsK[cur][row * 64 + (cb >> 1)];
        }

      f32x4 sc[2][4];
#pragma unroll
      for (int mt = 0; mt < 2; ++mt)
#pragma unroll
        for (int nt = 0; nt < 4; ++nt) {
          f32x4 a = {0.f, 0.f, 0.f, 0.f};
          a = __builtin_amdgcn_mfma_f32_16x16x32_bf16(qa[mt][0], kb[nt][0], a, 0, 0, 0);
          a = __builtin_amdgcn_mfma_f32_16x16x32_bf16(qa[mt][1], kb[nt][1], a, 0, 0, 0);
          sc[mt][nt] = a;
        }

      const bool diag = (kt == tendW);
#pragma unroll
      for (int mt = 0; mt < 2; ++mt) {
#pragma unroll
        for (int r = 0; r < 4; ++r) {
          const int qr = qbase + mt * 16 + (lane >> 4) * 4 + r;
          float vmax = -1e30f;
          if (diag) {
#pragma unroll
            for (int nt = 0; nt < 4; ++nt) {
              const int col = k0 + nt * 16 + (lane & 15);
              float sv = (col > qr) ? -1e30f : sc[mt][nt][r];
              sc[mt][nt][r] = sv;
              vmax = fmaxf(vmax, sv);
            }
          } else {
#pragma unroll
            for (int nt = 0; nt < 4; ++nt) vmax = fmaxf(vmax, sc[mt][nt][r]);
          }
#pragma unroll
          for (int off = 1; off < 16; off <<= 1) vmax = fmaxf(vmax, __shfl_xor(vmax, off));
          // defer-max (T13): rescale only when tile max exceeds running max by >7 (log2)
          float m = mrun[mt][r];
          if (vmax > m + 7.f) {
            const float al = exp2f(m - vmax);
            mrun[mt][r] = vmax; m = vmax;
            lrun[mt][r] *= al;
#pragma unroll
            for (int nt = 0; nt < 4; ++nt) oacc[mt][nt][r] *= al;
          }
          float rs = 0.f;
#pragma unroll
          for (int nt = 0; nt < 4; ++nt) {
            float p = exp2f(sc[mt][nt][r] - m);
            sc[mt][nt][r] = p;
            rs += p;
          }
#pragma unroll
          for (int off = 1; off < 16; off <<= 1) rs += __shfl_xor(rs, off);
          lrun[mt][r] += rs;
        }
      }

      // P (D-frag layout) -> LDS -> A-frag layout (per-wave private buffer)
#pragma unroll
      for (int mt = 0; mt < 2; ++mt)
#pragma unroll
        for (int nt = 0; nt < 4; ++nt)
#pragma unroll
          for (int r = 0; r < 4; ++r)
            Pw[(mt * 16 + (lane >> 4) * 4 + r) * 72 + nt * 16 + (lane & 15)] = f2bf(sc[mt][nt][r]);
      asm volatile("s_waitcnt lgkmcnt(0)" ::: "memory");
      __builtin_amdgcn_sched_barrier(0);

      bf16x8 pa[2][2];
#pragma unroll
      for (int mt = 0; mt < 2; ++mt)
#pragma unroll
        for (int kk = 0; kk < 2; ++kk)
          pa[mt][kk] = *(const bf16x8*)&Pw[(mt * 16 + (lane & 15)) * 72 + kk * 32 + (lane >> 4) * 8];
      __builtin_amdgcn_sched_barrier(0);

      // V frags from LDS (swizzled read offsets)
#pragma unroll
      for (int nt = 0; nt < 4; ++nt) {
        const int row = nt * 16 + (lane & 15);  // d index
        bf16x8 vb0, vb1;
        {
          const int cb = (((lane >> 4) << 4)) ^ ((row & 7) << 4);
          vb0 = *(const bf16x8*)&lsV[cur][row * 64 + (cb >> 1)];
        }
        {
          const int cb = (64 + ((lane >> 4) << 4)) ^ ((row & 7) << 4);
          vb1 = *(const bf16x8*)&lsV[cur][row * 64 + (cb >> 1)];
        }
#pragma unroll
        for (int mt = 0; mt < 2; ++mt) {
          oacc[mt][nt] = __builtin_amdgcn_mfma_f32_16x16x32_bf16(pa[mt][0], vb0, oacc[mt][nt], 0, 0, 0);
          oacc[mt][nt] = __builtin_amdgcn_mfma_f32_16x16x32_bf16(pa[mt][1], vb1, oacc[mt][nt], 0, 0, 0);
        }
      }
    }

    __syncthreads();  // stage(kt+1) complete (vmcnt drain) + all waves done with cur
    cur ^= 1;
  }

#pragma unroll
  for (int mt = 0; mt < 2; ++mt)
#pragma unroll
    for (int r = 0; r < 4; ++r) {
      const int s = qbase + mt * 16 + (lane >> 4) * 4 + r;
      const float inv = 1.f / lrun[mt][r];
#pragma unroll
      for (int nt = 0; nt < 4; ++nt) {
        const int dd = nt * 16 + (lane & 15);
        AO[((size_t)(b * SEQ + s) * NH + h) * 64 + dd] = f2bf(oacc[mt][nt][r] * inv);
      }
    }
}

extern "C" void kernel_launch(void* const* d_in, const int* in_sizes, int n_in,
                              void* d_out, int out_size, void* d_ws, size_t ws_size,
                              hipStream_t stream) {
  const float* x  = (const float*)d_in[0];
  const int*   pos = (const int*)d_in[1];
  const float* Wq = (const float*)d_in[2];
  const float* Wk = (const float*)d_in[3];
  const float* Wv = (const float*)d_in[4];
  const float* Wo = (const float*)d_in[5];
  float* out = (float*)d_out;
  char* ws = (char*)d_ws;
  const size_t MB = 1024 * 1024;
  if (ws_size < 73 * MB) return;  // refuse to scribble OOB

  u16* xb  = (u16*)(ws);             // 16MB; re-used as AO after QKV proj
  u16* wqb = (u16*)(ws + 16 * MB);
  u16* wkb = (u16*)(ws + 18 * MB);
  u16* wvb = (u16*)(ws + 20 * MB);
  u16* wob = (u16*)(ws + 22 * MB);
  u16* Qh  = (u16*)(ws + 24 * MB);
  u16* Kh  = (u16*)(ws + 40 * MB);
  u16* Vt  = (u16*)(ws + 56 * MB);
  float2* tab = (float2*)(ws + 72 * MB);
  u16* AO = xb;

  cast_bf16_k<<<(MTOT * DM / 4) / 256, 256, 0, stream>>>(x, xb, MTOT * DM / 4);
  cast_bf16_k<<<(DM * DM / 4) / 256, 256, 0, stream>>>(Wq, wqb, DM * DM / 4);
  cast_bf16_k<<<(DM * DM / 4) / 256, 256, 0, stream>>>(Wk, wkb, DM * DM / 4);
  cast_bf16_k<<<(DM * DM / 4) / 256, 256, 0, stream>>>(Wv, wvb, DM * DM / 4);
  cast_bf16_k<<<(DM * DM / 4) / 256, 256, 0, stream>>>(Wo, wob, DM * DM / 4);
  rope_tab_k<<<(SEQ * 32) / 256, 256, 0, stream>>>(pos, tab);

  gemm_bt<1><<<dim3(8, 64, 3), 256, 0, stream>>>(xb, wqb, wkb, wvb, nullptr, Qh, Kh, Vt, tab);
  attn_k<<<dim3(1024), 256, 0, stream>>>(Qh, Kh, Vt, AO);
  gemm_bt<0><<<dim3(8, 64, 1), 256, 0, stream>>>(AO, wob, wob, wob, out, nullptr, nullptr, nullptr, nullptr);
}

// Round 7
// 272.465 us; speedup vs baseline: 1.6807x; 1.1068x over previous
//
#include <hip/hip_runtime.h>

#define SEQ   2048
#define BATCH 4
#define NH    16
#define DM    1024
#define MTOT  (BATCH*SEQ)   // 8192

typedef unsigned short u16;
typedef unsigned int   u32;
typedef __attribute__((ext_vector_type(8)))  __bf16 bf16x8;
typedef __attribute__((ext_vector_type(4)))  float  f32x4;
typedef __attribute__((ext_vector_type(16))) float  f32x16;
typedef __attribute__((address_space(1))) u32 as1_u32;
typedef __attribute__((address_space(3))) u32 as3_u32;

__device__ __forceinline__ u16 f2bf(float f) {
  union { float f; u32 u; } c; c.f = f;
  return (u16)((c.u + 0x7fffu + ((c.u >> 16) & 1u)) >> 16);
}

__global__ void cast_bf16_k(const float* __restrict__ in, u16* __restrict__ out, int n4) {
  int i = blockIdx.x * blockDim.x + threadIdx.x;
  if (i < n4) {
    float4 v = reinterpret_cast<const float4*>(in)[i];
    ushort4 o;
    o.x = f2bf(v.x); o.y = f2bf(v.y); o.z = f2bf(v.z); o.w = f2bf(v.w);
    reinterpret_cast<ushort4*>(out)[i] = o;
  }
}

__global__ void rope_tab_k(const int* __restrict__ pos, float2* __restrict__ tab) {
  int i = blockIdx.x * blockDim.x + threadIdx.x;  // s*32 + j
  if (i < SEQ * 32) {
    int s = i >> 5, j = i & 31;
    float p = (float)pos[s];
    float fr = powf(10000.f, -(float)j / 32.f);
    float a = p * fr;
    tab[i] = make_float2(cosf(a), sinf(a));
  }
}

// C = A @ Bt^T.  A: [M,1024] bf16 row-major. Bt: [1024,1024] bf16 row-major ([N][K]).
// EPI 0: fp32 store to outF. EPI 1: z=0/1 -> RoPE -> Qh/Kh [B,H,S,64]; z=2 -> Vt [B,H,64,S].
// Q additionally scaled by 0.125*log2(e) so attention can use exp2 with no extra mult.
template<int EPI>
__global__ __launch_bounds__(256)
void gemm_bt(const u16* __restrict__ A,
             const u16* __restrict__ B0, const u16* __restrict__ B1, const u16* __restrict__ B2,
             float* __restrict__ outF,
             u16* __restrict__ Qh, u16* __restrict__ Kh, u16* __restrict__ Vt,
             const float2* __restrict__ tab) {
  const int K = DM, N = DM;
  __shared__ u16 lsA[128 * 32];
  __shared__ u16 lsB[128 * 32];
  const int t = threadIdx.x;
  const int lane = t & 63;
  const int wid = t >> 6;
  const int wr = wid >> 1, wc = wid & 1;
  const int m0 = blockIdx.y * 128, n0 = blockIdx.x * 128;
  const int z = blockIdx.z;
  const u16* Bt = (z == 0) ? B0 : (z == 1 ? B1 : B2);

  f32x4 acc[4][4] = {};

  const int srow = t >> 2;
  const int scol = (t & 3) * 8;
  const u16* gA = A + (size_t)(m0 + srow) * K + scol;
  const u16* gB = Bt + (size_t)(n0 + srow) * K + scol;
  const u32 lo = (u32)t * 16u;

  for (int kt = 0; kt < K; kt += 32) {
    __builtin_amdgcn_global_load_lds((const as1_u32*)(gA + kt),
                                     (as3_u32*)((char*)lsA + lo), 16, 0, 0);
    __builtin_amdgcn_global_load_lds((const as1_u32*)(gA + (size_t)64 * K + kt),
                                     (as3_u32*)((char*)lsA + 4096 + lo), 16, 0, 0);
    __builtin_amdgcn_global_load_lds((const as1_u32*)(gB + kt),
                                     (as3_u32*)((char*)lsB + lo), 16, 0, 0);
    __builtin_amdgcn_global_load_lds((const as1_u32*)(gB + (size_t)64 * K + kt),
                                     (as3_u32*)((char*)lsB + 4096 + lo), 16, 0, 0);
    __syncthreads();
    bf16x8 af[4], bfr[4];
#pragma unroll
    for (int mt = 0; mt < 4; ++mt)
      af[mt] = *(const bf16x8*)&lsA[(wr * 64 + mt * 16 + (lane & 15)) * 32 + (lane >> 4) * 8];
#pragma unroll
    for (int nt = 0; nt < 4; ++nt)
      bfr[nt] = *(const bf16x8*)&lsB[(wc * 64 + nt * 16 + (lane & 15)) * 32 + (lane >> 4) * 8];
#pragma unroll
    for (int mt = 0; mt < 4; ++mt)
#pragma unroll
      for (int nt = 0; nt < 4; ++nt)
        acc[mt][nt] = __builtin_amdgcn_mfma_f32_16x16x32_bf16(af[mt], bfr[nt], acc[mt][nt], 0, 0, 0);
    __syncthreads();
  }

#pragma unroll
  for (int mt = 0; mt < 4; ++mt) {
    const int gmb = m0 + wr * 64 + mt * 16 + (lane >> 4) * 4;
#pragma unroll
    for (int nt = 0; nt < 4; ++nt) {
      const int gn = n0 + wc * 64 + nt * 16 + (lane & 15);
#pragma unroll
      for (int r = 0; r < 4; ++r) {
        float v = acc[mt][nt][r];
        if (EPI == 0) {
          outF[(size_t)(gmb + r) * N + gn] = v;
        } else {
          const int row = gmb + r;
          const int b = row >> 11, s = row & (SEQ - 1);
          const int h = gn >> 6, dd = gn & 63;
          if (z < 2) {
            float p = __shfl_xor(v, 1);
            const float2 cs = tab[(s << 5) + (dd >> 1)];
            float o = ((lane & 1) == 0) ? (v * cs.x - p * cs.y) : (p * cs.y + v * cs.x);
            if (z == 0) o *= 0.18033688011112042f;  // 0.125 * log2(e)
            u16* dst = z ? Kh : Qh;
            dst[((size_t)((b * NH + h) * SEQ + s) << 6) + dd] = f2bf(o);
          } else {
            Vt[((size_t)((b * NH + h) << 6) + dd) * SEQ + s] = f2bf(v);
          }
        }
      }
    }
  }
}

// Flash attention, causal, log2-domain softmax, SWAPPED-OPERAND 32x32x16 MFMA.
// S^T = K.Q^T -> each lane owns one q-row (col=lane&31) with k = (r&3)+8*(r>>2)+4*hi
// per 32-k tile -> softmax fully in-register (+1 shfl_xor(32) for the row max / sum).
// PV also swapped: O^T = V^T . P^T; V^T A-frags are contiguous 16B reads from the
// d-major Vt; P^T B-frags built via v_cvt_pk_bf16_f32 + one shfl_xor(32) per pair.
// No LDS, no barriers; waves independent. Grid 1024 = 16 ranks x 64 bh (heavy-first,
// bid%8 = bh%8 XCD-uniform); block's 4 waves take 4 consecutive 32-row chunks.
// NOTE: no min-waves launch_bounds -- forcing 4/EU spilled ~1GB to scratch (R3).
__global__ __launch_bounds__(256)
void attn_k(const u16* __restrict__ Qh, const u16* __restrict__ Kh,
            const u16* __restrict__ Vt, u16* __restrict__ AO) {
  const int t = threadIdx.x, lane = t & 63, w = t >> 6;
  const int hiL = lane >> 5;
  const int q31 = lane & 31;
  const int bid = blockIdx.x;
  const int bh = bid & 63, b = bh >> 4, h = bh & 15;
  const int qc = 63 - ((bid >> 6) * 4 + w);   // heavy-first
  const int qbase = qc * 32;
  const int tend = (qbase + 31) >> 6;
  const u16* Qp = Qh + (size_t)bh * SEQ * 64;
  const u16* Kp = Kh + (size_t)bh * SEQ * 64;
  const u16* Vp = Vt + (size_t)bh * 64 * SEQ;

  // Q B-frags (col = q = lane&31, k-slice = kc*16 + hi*8)
  bf16x8 qa[4];
#pragma unroll
  for (int kc = 0; kc < 4; ++kc)
    qa[kc] = *(const bf16x8*)(Qp + (size_t)(qbase + q31) * 64 + kc * 16 + hiL * 8);

  f32x16 O0 = {}, O1 = {};   // O^T frags: d-tiles 0..31 / 32..63, col=q
  float m = -1e30f, l = 0.f;

  for (int kt = 0; kt <= tend; ++kt) {
    const int k0 = kt * 64;

    // QK^T swapped: A = K rows (contiguous 16B)
    f32x16 S0 = {}, S1 = {};
    const u16* Krow0 = Kp + (size_t)(k0 + q31) * 64 + hiL * 8;
#pragma unroll
    for (int kc = 0; kc < 4; ++kc) {
      bf16x8 ka = *(const bf16x8*)(Krow0 + kc * 16);
      S0 = __builtin_amdgcn_mfma_f32_32x32x16_bf16(ka, qa[kc], S0, 0, 0, 0);
    }
#pragma unroll
    for (int kc = 0; kc < 4; ++kc) {
      bf16x8 ka = *(const bf16x8*)(Krow0 + 32 * 64 + kc * 16);
      S1 = __builtin_amdgcn_mfma_f32_32x32x16_bf16(ka, qa[kc], S1, 0, 0, 0);
    }

    // V^T A-frags issued early -- fly during softmax
    bf16x8 va[2][4];
#pragma unroll
    for (int dt = 0; dt < 2; ++dt)
#pragma unroll
      for (int kc = 0; kc < 4; ++kc)
        va[dt][kc] = *(const bf16x8*)(Vp + (size_t)(dt * 32 + q31) * SEQ + k0 + kc * 16 + hiL * 8);

    // causal mask (diag tile only); k = k0 + [32*kv] + (r&3)+8*(r>>2)+4*hi
    if (kt == tend) {
      const int qg = qbase + q31;
#pragma unroll
      for (int r = 0; r < 16; ++r) {
        const int kg = k0 + (r & 3) + 8 * (r >> 2) + 4 * hiL;
        S0[r] = (kg > qg) ? -1e30f : S0[r];
        S1[r] = (kg + 32 > qg) ? -1e30f : S1[r];
      }
    }

    // in-register row max (+ pair-lane combine)
    float vmax = -1e30f;
#pragma unroll
    for (int r = 0; r < 16; ++r) {
      vmax = fmaxf(vmax, S0[r]);
      vmax = fmaxf(vmax, S1[r]);
    }
    vmax = fmaxf(vmax, __shfl_xor(vmax, 32));

    // defer-max (T13): rescale only when tile max exceeds running max by >7 (log2)
    if (vmax > m + 7.f) {
      const float al = exp2f(m - vmax);
      m = vmax; l *= al;
#pragma unroll
      for (int r = 0; r < 16; ++r) { O0[r] *= al; O1[r] *= al; }
    }

    // exp2 + per-lane partial sum (combined with partner only at epilogue)
    float rs = 0.f;
#pragma unroll
    for (int r = 0; r < 16; ++r) {
      const float p0 = exp2f(S0[r] - m);
      const float p1 = exp2f(S1[r] - m);
      S0[r] = p0; S1[r] = p1;
      rs += p0 + p1;
    }
    l += rs;

    // P^T B-frags: pack pairs to bf16, exchange halves with lane^32.
    // quadLow  (r = 8*kb+0..3): k%16 = {0..3}+4hi ; quadHigh: {8..11}+4hi.
    // hi=0 frag = [own qL | partner qL]; hi=1 frag = [partner qH | own qH].
    bf16x8 pb[4];
#define PACKKC(SV, kb, OUT)                                                         \
    {                                                                               \
      u32 qL0, qL1, qH0, qH1;                                                       \
      asm("v_cvt_pk_bf16_f32 %0, %1, %2" : "=v"(qL0) : "v"(SV[8*(kb)+0]), "v"(SV[8*(kb)+1])); \
      asm("v_cvt_pk_bf16_f32 %0, %1, %2" : "=v"(qL1) : "v"(SV[8*(kb)+2]), "v"(SV[8*(kb)+3])); \
      asm("v_cvt_pk_bf16_f32 %0, %1, %2" : "=v"(qH0) : "v"(SV[8*(kb)+4]), "v"(SV[8*(kb)+5])); \
      asm("v_cvt_pk_bf16_f32 %0, %1, %2" : "=v"(qH1) : "v"(SV[8*(kb)+6]), "v"(SV[8*(kb)+7])); \
      const u32 sA = hiL ? qL0 : qH0;                                               \
      const u32 sB = hiL ? qL1 : qH1;                                               \
      const u32 rA = (u32)__shfl_xor((int)sA, 32);                                  \
      const u32 rB = (u32)__shfl_xor((int)sB, 32);                                  \
      union { u32 wds[4]; bf16x8 v; } uu;                                           \
      uu.wds[0] = hiL ? rA : qL0;                                                   \
      uu.wds[1] = hiL ? rB : qL1;                                                   \
      uu.wds[2] = hiL ? qH0 : rA;                                                   \
      uu.wds[3] = hiL ? qH1 : rB;                                                   \
      OUT = uu.v;                                                                   \
    }
    PACKKC(S0, 0, pb[0])
    PACKKC(S0, 1, pb[1])
    PACKKC(S1, 0, pb[2])
    PACKKC(S1, 1, pb[3])
#undef PACKKC

    // O^T += V^T . P^T
#pragma unroll
    for (int kc = 0; kc < 4; ++kc) {
      O0 = __builtin_amdgcn_mfma_f32_32x32x16_bf16(va[0][kc], pb[kc], O0, 0, 0, 0);
      O1 = __builtin_amdgcn_mfma_f32_32x32x16_bf16(va[1][kc], pb[kc], O1, 0, 0, 0);
    }
  }

  // epilogue: combine partner partial sums, normalize, store bf16 pairs
  l += __shfl_xor(l, 32);
  const float inv = 1.f / l;
  const int s = qbase + q31;
  u16* dst = AO + ((size_t)(b * SEQ + s) * NH + h) * 64;
#pragma unroll
  for (int rp = 0; rp < 8; ++rp) {
    const int r = rp * 2;
    const int d = (r & 3) + 8 * (r >> 2) + 4 * hiL;
    u32 w0, w1;
    asm("v_cvt_pk_bf16_f32 %0, %1, %2" : "=v"(w0) : "v"(O0[r] * inv), "v"(O0[r + 1] * inv));
    asm("v_cvt_pk_bf16_f32 %0, %1, %2" : "=v"(w1) : "v"(O1[r] * inv), "v"(O1[r + 1] * inv));
    *reinterpret_cast<u32*>(dst + d) = w0;
    *reinterpret_cast<u32*>(dst + 32 + d) = w1;
  }
}

extern "C" void kernel_launch(void* const* d_in, const int* in_sizes, int n_in,
                              void* d_out, int out_size, void* d_ws, size_t ws_size,
                              hipStream_t stream) {
  const float* x  = (const float*)d_in[0];
  const int*   pos = (const int*)d_in[1];
  const float* Wq = (const float*)d_in[2];
  const float* Wk = (const float*)d_in[3];
  const float* Wv = (const float*)d_in[4];
  const float* Wo = (const float*)d_in[5];
  float* out = (float*)d_out;
  char* ws = (char*)d_ws;
  const size_t MB = 1024 * 1024;
  if (ws_size < 73 * MB) return;  // refuse to scribble OOB

  u16* xb  = (u16*)(ws);             // 16MB; re-used as AO after QKV proj
  u16* wqb = (u16*)(ws + 16 * MB);
  u16* wkb = (u16*)(ws + 18 * MB);
  u16* wvb = (u16*)(ws + 20 * MB);
  u16* wob = (u16*)(ws + 22 * MB);
  u16* Qh  = (u16*)(ws + 24 * MB);
  u16* Kh  = (u16*)(ws + 40 * MB);
  u16* Vt  = (u16*)(ws + 56 * MB);
  float2* tab = (float2*)(ws + 72 * MB);
  u16* AO = xb;

  cast_bf16_k<<<(MTOT * DM / 4) / 256, 256, 0, stream>>>(x, xb, MTOT * DM / 4);
  cast_bf16_k<<<(DM * DM / 4) / 256, 256, 0, stream>>>(Wq, wqb, DM * DM / 4);
  cast_bf16_k<<<(DM * DM / 4) / 256, 256, 0, stream>>>(Wk, wkb, DM * DM / 4);
  cast_bf16_k<<<(DM * DM / 4) / 256, 256, 0, stream>>>(Wv, wvb, DM * DM / 4);
  cast_bf16_k<<<(DM * DM / 4) / 256, 256, 0, stream>>>(Wo, wob, DM * DM / 4);
  rope_tab_k<<<(SEQ * 32) / 256, 256, 0, stream>>>(pos, tab);

  gemm_bt<1><<<dim3(8, 64, 3), 256, 0, stream>>>(xb, wqb, wkb, wvb, nullptr, Qh, Kh, Vt, tab);
  attn_k<<<dim3(1024), 256, 0, stream>>>(Qh, Kh, Vt, AO);
  gemm_bt<0><<<dim3(8, 64, 1), 256, 0, stream>>>(AO, wob, wob, wob, out, nullptr, nullptr, nullptr, nullptr);
}

// Round 8
// 230.196 us; speedup vs baseline: 1.9893x; 1.1836x over previous
//
#include <hip/hip_runtime.h>

#define SEQ   2048
#define BATCH 4
#define NH    16
#define DM    1024
#define MTOT  (BATCH*SEQ)   // 8192

typedef unsigned short u16;
typedef unsigned int   u32;
typedef __attribute__((ext_vector_type(8)))  __bf16 bf16x8;
typedef __attribute__((ext_vector_type(4)))  float  f32x4;
typedef __attribute__((ext_vector_type(16))) float  f32x16;
typedef __attribute__((address_space(1))) u32 as1_u32;
typedef __attribute__((address_space(3))) u32 as3_u32;

__device__ __forceinline__ u16 f2bf(float f) {
  union { float f; u32 u; } c; c.f = f;
  return (u16)((c.u + 0x7fffu + ((c.u >> 16) & 1u)) >> 16);
}

__global__ void cast_bf16_k(const float* __restrict__ in, u16* __restrict__ out, int n4) {
  int i = blockIdx.x * blockDim.x + threadIdx.x;
  if (i < n4) {
    float4 v = reinterpret_cast<const float4*>(in)[i];
    ushort4 o;
    o.x = f2bf(v.x); o.y = f2bf(v.y); o.z = f2bf(v.z); o.w = f2bf(v.w);
    reinterpret_cast<ushort4*>(out)[i] = o;
  }
}

__global__ void rope_tab_k(const int* __restrict__ pos, float2* __restrict__ tab) {
  int i = blockIdx.x * blockDim.x + threadIdx.x;  // s*32 + j
  if (i < SEQ * 32) {
    int s = i >> 5, j = i & 31;
    float p = (float)pos[s];
    float fr = powf(10000.f, -(float)j / 32.f);
    float a = p * fr;
    tab[i] = make_float2(cosf(a), sinf(a));
  }
}

// C = A @ Bt^T.  A: [M,1024] bf16 row-major. Bt: [1024,1024] bf16 row-major ([N][K]).
// EPI 0: fp32 store to outF. EPI 1: z=0/1 -> RoPE -> Qh/Kh [B,H,S,64]; z=2 -> Vt [B,H,64,S].
// Q additionally scaled by 0.125*log2(e) so attention can use exp2 with no extra mult.
template<int EPI>
__global__ __launch_bounds__(256)
void gemm_bt(const u16* __restrict__ A,
             const u16* __restrict__ B0, const u16* __restrict__ B1, const u16* __restrict__ B2,
             float* __restrict__ outF,
             u16* __restrict__ Qh, u16* __restrict__ Kh, u16* __restrict__ Vt,
             const float2* __restrict__ tab) {
  const int K = DM, N = DM;
  __shared__ u16 lsA[128 * 32];
  __shared__ u16 lsB[128 * 32];
  const int t = threadIdx.x;
  const int lane = t & 63;
  const int wid = t >> 6;
  const int wr = wid >> 1, wc = wid & 1;
  const int m0 = blockIdx.y * 128, n0 = blockIdx.x * 128;
  const int z = blockIdx.z;
  const u16* Bt = (z == 0) ? B0 : (z == 1 ? B1 : B2);

  f32x4 acc[4][4] = {};

  const int srow = t >> 2;
  const int scol = (t & 3) * 8;
  const u16* gA = A + (size_t)(m0 + srow) * K + scol;
  const u16* gB = Bt + (size_t)(n0 + srow) * K + scol;
  const u32 lo = (u32)t * 16u;

  for (int kt = 0; kt < K; kt += 32) {
    __builtin_amdgcn_global_load_lds((const as1_u32*)(gA + kt),
                                     (as3_u32*)((char*)lsA + lo), 16, 0, 0);
    __builtin_amdgcn_global_load_lds((const as1_u32*)(gA + (size_t)64 * K + kt),
                                     (as3_u32*)((char*)lsA + 4096 + lo), 16, 0, 0);
    __builtin_amdgcn_global_load_lds((const as1_u32*)(gB + kt),
                                     (as3_u32*)((char*)lsB + lo), 16, 0, 0);
    __builtin_amdgcn_global_load_lds((const as1_u32*)(gB + (size_t)64 * K + kt),
                                     (as3_u32*)((char*)lsB + 4096 + lo), 16, 0, 0);
    __syncthreads();
    bf16x8 af[4], bfr[4];
#pragma unroll
    for (int mt = 0; mt < 4; ++mt)
      af[mt] = *(const bf16x8*)&lsA[(wr * 64 + mt * 16 + (lane & 15)) * 32 + (lane >> 4) * 8];
#pragma unroll
    for (int nt = 0; nt < 4; ++nt)
      bfr[nt] = *(const bf16x8*)&lsB[(wc * 64 + nt * 16 + (lane & 15)) * 32 + (lane >> 4) * 8];
#pragma unroll
    for (int mt = 0; mt < 4; ++mt)
#pragma unroll
      for (int nt = 0; nt < 4; ++nt)
        acc[mt][nt] = __builtin_amdgcn_mfma_f32_16x16x32_bf16(af[mt], bfr[nt], acc[mt][nt], 0, 0, 0);
    __syncthreads();
  }

#pragma unroll
  for (int mt = 0; mt < 4; ++mt) {
    const int gmb = m0 + wr * 64 + mt * 16 + (lane >> 4) * 4;
#pragma unroll
    for (int nt = 0; nt < 4; ++nt) {
      const int gn = n0 + wc * 64 + nt * 16 + (lane & 15);
#pragma unroll
      for (int r = 0; r < 4; ++r) {
        float v = acc[mt][nt][r];
        if (EPI == 0) {
          outF[(size_t)(gmb + r) * N + gn] = v;
        } else {
          const int row = gmb + r;
          const int b = row >> 11, s = row & (SEQ - 1);
          const int h = gn >> 6, dd = gn & 63;
          if (z < 2) {
            float p = __shfl_xor(v, 1);
            const float2 cs = tab[(s << 5) + (dd >> 1)];
            float o = ((lane & 1) == 0) ? (v * cs.x - p * cs.y) : (p * cs.y + v * cs.x);
            if (z == 0) o *= 0.18033688011112042f;  // 0.125 * log2(e)
            u16* dst = z ? Kh : Qh;
            dst[((size_t)((b * NH + h) * SEQ + s) << 6) + dd] = f2bf(o);
          } else {
            Vt[((size_t)((b * NH + h) << 6) + dd) * SEQ + s] = f2bf(v);
          }
        }
      }
    }
  }
}

// Flash attention, causal, log2-domain softmax, SWAPPED-OPERAND 32x32x16 MFMA
// (in-register softmax, R7) + block-shared double-buffered LDS K/V staging via
// global_load_lds with XOR swizzle (R6). Grid 1024 = 64 bh x 16 ranks; block owns
// 128 q-rows (4 waves x 32); K/V 64x64 tiles staged once per block, one barrier/tile.
// NOTE: no min-waves launch_bounds -- forcing 4/EU spilled ~1GB to scratch (R3).
__global__ __launch_bounds__(256)
void attn_k(const u16* __restrict__ Qh, const u16* __restrict__ Kh,
            const u16* __restrict__ Vt, u16* __restrict__ AO) {
  __shared__ u16 lsK[2][64 * 64];
  __shared__ u16 lsV[2][64 * 64];
  const int t = threadIdx.x, lane = t & 63, w = t >> 6;
  const int hiL = lane >> 5;
  const int q31 = lane & 31;
  const int bid = blockIdx.x;
  const int bh = bid & 63, b = bh >> 4, h = bh & 15;
  const int chunk_blk = 15 - (bid >> 6);      // heavy-first
  const int qb_blk = chunk_blk * 128;
  const int tendB = (qb_blk + 127) >> 6;      // block's last K-tile
  const int qbase = qb_blk + w * 32;          // this wave's 32 q-rows
  const int tendW = (qbase + 31) >> 6;        // this wave's last K-tile
  const u16* Qp = Qh + (size_t)bh * SEQ * 64;
  const u16* Kp = Kh + (size_t)bh * SEQ * 64;
  const u16* Vp = Vt + (size_t)bh * 64 * SEQ;

  // Q B-frags (col = q = lane&31, k-slice = kc*16 + hi*8)
  bf16x8 qa[4];
#pragma unroll
  for (int kc = 0; kc < 4; ++kc)
    qa[kc] = *(const bf16x8*)(Qp + (size_t)(qbase + q31) * 64 + kc * 16 + hiL * 8);

  f32x16 O0 = {}, O1 = {};   // O^T frags: d-tiles 0..31 / 32..63, col=q
  float m = -1e30f, l = 0.f;

  // ---- stage tile kt into buffer bf (all 256 threads cooperate) ----
  // LDS: linear dest; logical col-byte c of row stored at c ^ ((row&7)<<4).
  // Writer pre-swizzles the GLOBAL source column (both-sides rule).
#define STAGE(bf, kt_)                                                                  \
  {                                                                                     \
    const int k0s = (kt_) * 64;                                                         \
    _Pragma("unroll")                                                                   \
    for (int hh = 0; hh < 2; ++hh) {                                                    \
      const int idx = hh * 256 + t;                                                     \
      const int row = idx >> 3;                                                         \
      const int cb = ((idx & 7) << 4) ^ ((row & 7) << 4);                               \
      __builtin_amdgcn_global_load_lds((const as1_u32*)(Kp + (size_t)(k0s + row) * 64 + (cb >> 1)), \
                                       (as3_u32*)((char*)&lsK[bf][0] + idx * 16), 16, 0, 0); \
      __builtin_amdgcn_global_load_lds((const as1_u32*)(Vp + (size_t)row * SEQ + k0s + (cb >> 1)), \
                                       (as3_u32*)((char*)&lsV[bf][0] + idx * 16), 16, 0, 0); \
    }                                                                                   \
  }

  STAGE(0, 0);
  __syncthreads();
  int cur = 0;

  for (int kt = 0; kt <= tendB; ++kt) {
    if (kt < tendB) STAGE(cur ^ 1, kt + 1);  // next tile DMAs during compute

    if (kt <= tendW) {
      const int k0 = kt * 64;
      const int swz = (q31 & 7) << 4;

      // K A-frags from LDS (swizzled read offsets); S^T = K . Q^T
      f32x16 S0 = {}, S1 = {};
#pragma unroll
      for (int kc = 0; kc < 4; ++kc) {
        const int cb = (kc * 32 + hiL * 16) ^ swz;
        bf16x8 ka = *(const bf16x8*)&lsK[cur][q31 * 64 + (cb >> 1)];
        S0 = __builtin_amdgcn_mfma_f32_32x32x16_bf16(ka, qa[kc], S0, 0, 0, 0);
      }
#pragma unroll
      for (int kc = 0; kc < 4; ++kc) {
        const int cb = (kc * 32 + hiL * 16) ^ swz;
        bf16x8 ka = *(const bf16x8*)&lsK[cur][(32 + q31) * 64 + (cb >> 1)];
        S1 = __builtin_amdgcn_mfma_f32_32x32x16_bf16(ka, qa[kc], S1, 0, 0, 0);
      }

      // causal mask (diag tile only); k = k0 + [32*kv] + (r&3)+8*(r>>2)+4*hi
      if (kt == tendW) {
        const int qg = qbase + q31;
#pragma unroll
        for (int r = 0; r < 16; ++r) {
          const int kg = k0 + (r & 3) + 8 * (r >> 2) + 4 * hiL;
          S0[r] = (kg > qg) ? -1e30f : S0[r];
          S1[r] = (kg + 32 > qg) ? -1e30f : S1[r];
        }
      }

      // in-register row max (+ pair-lane combine)
      float vmax = -1e30f;
#pragma unroll
      for (int r = 0; r < 16; ++r) {
        vmax = fmaxf(vmax, S0[r]);
        vmax = fmaxf(vmax, S1[r]);
      }
      vmax = fmaxf(vmax, __shfl_xor(vmax, 32));

      // defer-max (T13): rescale only when tile max exceeds running max by >7 (log2)
      if (vmax > m + 7.f) {
        const float al = exp2f(m - vmax);
        m = vmax; l *= al;
#pragma unroll
        for (int r = 0; r < 16; ++r) { O0[r] *= al; O1[r] *= al; }
      }

      // exp2 + per-lane partial sum (partner-combined at epilogue)
      float rs = 0.f;
#pragma unroll
      for (int r = 0; r < 16; ++r) {
        const float p0 = exp2f(S0[r] - m);
        const float p1 = exp2f(S1[r] - m);
        S0[r] = p0; S1[r] = p1;
        rs += p0 + p1;
      }
      l += rs;

      // P^T B-frags: pack pairs to bf16, exchange halves with lane^32.
      bf16x8 pb[4];
#define PACKKC(SV, kb, OUT)                                                         \
      {                                                                             \
        u32 qL0, qL1, qH0, qH1;                                                     \
        asm("v_cvt_pk_bf16_f32 %0, %1, %2" : "=v"(qL0) : "v"(SV[8*(kb)+0]), "v"(SV[8*(kb)+1])); \
        asm("v_cvt_pk_bf16_f32 %0, %1, %2" : "=v"(qL1) : "v"(SV[8*(kb)+2]), "v"(SV[8*(kb)+3])); \
        asm("v_cvt_pk_bf16_f32 %0, %1, %2" : "=v"(qH0) : "v"(SV[8*(kb)+4]), "v"(SV[8*(kb)+5])); \
        asm("v_cvt_pk_bf16_f32 %0, %1, %2" : "=v"(qH1) : "v"(SV[8*(kb)+6]), "v"(SV[8*(kb)+7])); \
        const u32 sA = hiL ? qL0 : qH0;                                             \
        const u32 sB = hiL ? qL1 : qH1;                                             \
        const u32 rA = (u32)__shfl_xor((int)sA, 32);                                \
        const u32 rB = (u32)__shfl_xor((int)sB, 32);                                \
        union { u32 wds[4]; bf16x8 v; } uu;                                         \
        uu.wds[0] = hiL ? rA : qL0;                                                 \
        uu.wds[1] = hiL ? rB : qL1;                                                 \
        uu.wds[2] = hiL ? qH0 : rA;                                                 \
        uu.wds[3] = hiL ? qH1 : rB;                                                 \
        OUT = uu.v;                                                                 \
      }
      PACKKC(S0, 0, pb[0])
      PACKKC(S0, 1, pb[1])
      PACKKC(S1, 0, pb[2])
      PACKKC(S1, 1, pb[3])
#undef PACKKC

      // V^T A-frags from LDS (read late -- LDS latency is short), O^T += V^T . P^T
#pragma unroll
      for (int kc = 0; kc < 4; ++kc) {
        const int cb = (kc * 32 + hiL * 16) ^ swz;
        bf16x8 va0 = *(const bf16x8*)&lsV[cur][q31 * 64 + (cb >> 1)];
        bf16x8 va1 = *(const bf16x8*)&lsV[cur][(32 + q31) * 64 + (cb >> 1)];
        O0 = __builtin_amdgcn_mfma_f32_32x32x16_bf16(va0, pb[kc], O0, 0, 0, 0);
        O1 = __builtin_amdgcn_mfma_f32_32x32x16_bf16(va1, pb[kc], O1, 0, 0, 0);
      }
    }

    __syncthreads();  // stage(kt+1) drained + all waves done reading cur
    cur ^= 1;
  }

  // epilogue: combine partner partial sums, normalize, store bf16 pairs
  l += __shfl_xor(l, 32);
  const float inv = 1.f / l;
  const int s = qbase + q31;
  u16* dst = AO + ((size_t)(b * SEQ + s) * NH + h) * 64;
#pragma unroll
  for (int rp = 0; rp < 8; ++rp) {
    const int r = rp * 2;
    const int d = (r & 3) + 8 * (r >> 2) + 4 * hiL;
    u32 w0, w1;
    asm("v_cvt_pk_bf16_f32 %0, %1, %2" : "=v"(w0) : "v"(O0[r] * inv), "v"(O0[r + 1] * inv));
    asm("v_cvt_pk_bf16_f32 %0, %1, %2" : "=v"(w1) : "v"(O1[r] * inv), "v"(O1[r + 1] * inv));
    *reinterpret_cast<u32*>(dst + d) = w0;
    *reinterpret_cast<u32*>(dst + 32 + d) = w1;
  }
}

extern "C" void kernel_launch(void* const* d_in, const int* in_sizes, int n_in,
                              void* d_out, int out_size, void* d_ws, size_t ws_size,
                              hipStream_t stream) {
  const float* x  = (const float*)d_in[0];
  const int*   pos = (const int*)d_in[1];
  const float* Wq = (const float*)d_in[2];
  const float* Wk = (const float*)d_in[3];
  const float* Wv = (const float*)d_in[4];
  const float* Wo = (const float*)d_in[5];
  float* out = (float*)d_out;
  char* ws = (char*)d_ws;
  const size_t MB = 1024 * 1024;
  if (ws_size < 73 * MB) return;  // refuse to scribble OOB

  u16* xb  = (u16*)(ws);             // 16MB; re-used as AO after QKV proj
  u16* wqb = (u16*)(ws + 16 * MB);
  u16* wkb = (u16*)(ws + 18 * MB);
  u16* wvb = (u16*)(ws + 20 * MB);
  u16* wob = (u16*)(ws + 22 * MB);
  u16* Qh  = (u16*)(ws + 24 * MB);
  u16* Kh  = (u16*)(ws + 40 * MB);
  u16* Vt  = (u16*)(ws + 56 * MB);
  float2* tab = (float2*)(ws + 72 * MB);
  u16* AO = xb;

  cast_bf16_k<<<(MTOT * DM / 4) / 256, 256, 0, stream>>>(x, xb, MTOT * DM / 4);
  cast_bf16_k<<<(DM * DM / 4) / 256, 256, 0, stream>>>(Wq, wqb, DM * DM / 4);
  cast_bf16_k<<<(DM * DM / 4) / 256, 256, 0, stream>>>(Wk, wkb, DM * DM / 4);
  cast_bf16_k<<<(DM * DM / 4) / 256, 256, 0, stream>>>(Wv, wvb, DM * DM / 4);
  cast_bf16_k<<<(DM * DM / 4) / 256, 256, 0, stream>>>(Wo, wob, DM * DM / 4);
  rope_tab_k<<<(SEQ * 32) / 256, 256, 0, stream>>>(pos, tab);

  gemm_bt<1><<<dim3(8, 64, 3), 256, 0, stream>>>(xb, wqb, wkb, wvb, nullptr, Qh, Kh, Vt, tab);
  attn_k<<<dim3(1024), 256, 0, stream>>>(Qh, Kh, Vt, AO);
  gemm_bt<0><<<dim3(8, 64, 1), 256, 0, stream>>>(AO, wob, wob, wob, out, nullptr, nullptr, nullptr, nullptr);
}